// Round 9
// baseline (9002.562 us; speedup 1.0000x reference)
//
#include <hip/hip_runtime.h>
#include <hip/hip_bf16.h>
#include <hip/hip_fp16.h>

// Problem constants: N=100000, F=128, O=128, S=4, B=2, E=3200000
#define NN 100000
#define FF 128
#define OO 128
#define SS 4
#define BBASES 2
#define EE 3200000
#define TOTE (SS * EE)               // 12.8M edges total
#define RR 16                        // dest rows per bin (N % 16 == 0)
#define RSHIFT 4
#define NBINS ((NN + RR - 1) / RR)   // 6250
#define RBLOCKS 512                  // blocks for hist/reorder

// clang vector types usable with __builtin_nontemporal_* (HIP uint2/float4 are not)
typedef unsigned int uintx2 __attribute__((ext_vector_type(2)));
typedef float floatx4 __attribute__((ext_vector_type(4)));

// ===========================================================================
// out[n] = tanh( sum_b (sum_s Wc[s,b] * G_s[n]) @ W_b ),
//   G_s[n] = sum_{e in s: row_e=n} val_e * feat[col_e]
// Pipeline: bin 12.8M edges by dest row (16/bin) -> fp16 cast of feat ->
// fused kernel: 16-edge batches (double-buffered record broadcasts, 16
// independent 256B fp16 gathers pinned via sched_barrier, branch-free:
// 2 ds_adds/edge into per-support G_s), then Wc-fold GEMM + tanh epilogue.
// fp16 (not bf16): quantization error is linear in step; bf16 measured
// absmax 0.063 (3x threshold), fp16 step is 8x finer -> ~0.012 < 0.02.
// ===========================================================================

__global__ __launch_bounds__(256) void hist_kernel(const int* __restrict__ rows,
                                                   unsigned int* __restrict__ hist) {
  __shared__ unsigned int lh[NBINS];
  for (int i = threadIdx.x; i < NBINS; i += 256) lh[i] = 0;
  __syncthreads();
  const int stride = gridDim.x * 256;
  for (int i = blockIdx.x * 256 + threadIdx.x; i < TOTE; i += stride)
    atomicAdd(&lh[((unsigned)rows[i]) >> RSHIFT], 1u);
  __syncthreads();
  for (int i = threadIdx.x; i < NBINS; i += 256) {
    unsigned int c = lh[i];
    if (c) atomicAdd(&hist[i], c);
  }
}

__global__ __launch_bounds__(256) void scan_kernel(const unsigned int* __restrict__ hist,
                                                   unsigned int* __restrict__ bin_start,
                                                   unsigned int* __restrict__ cursor) {
  __shared__ unsigned int sums[256];
  const int C = (NBINS + 255) / 256;  // 25
  const int t = threadIdx.x;
  unsigned int s = 0;
  for (int j = 0; j < C; ++j) {
    int i = t * C + j;
    if (i < NBINS) s += hist[i];
  }
  sums[t] = s;
  __syncthreads();
  for (int off = 1; off < 256; off <<= 1) {
    unsigned int v = (t >= off) ? sums[t - off] : 0u;
    __syncthreads();
    sums[t] += v;
    __syncthreads();
  }
  unsigned int base = (t == 0) ? 0u : sums[t - 1];
  for (int j = 0; j < C; ++j) {
    int i = t * C + j;
    if (i < NBINS) {
      unsigned int h = hist[i];
      bin_start[i] = base;
      cursor[i] = base;
      base += h;
    }
  }
  if (t == 255) bin_start[NBINS] = base;  // == TOTE
}

__global__ __launch_bounds__(256) void reorder_kernel(
    const int* __restrict__ rows, const int* __restrict__ cols,
    const float* __restrict__ vals, unsigned int* __restrict__ cursor,
    uintx2* __restrict__ sorted) {
  __shared__ unsigned int lcnt[NBINS];
  __shared__ unsigned int lbase[NBINS];
  const int C = (TOTE + RBLOCKS - 1) / RBLOCKS;  // 25000
  const int start = blockIdx.x * C;
  const int end = min(start + C, TOTE);
  for (int i = threadIdx.x; i < NBINS; i += 256) lcnt[i] = 0;
  __syncthreads();
  for (int i = start + threadIdx.x; i < end; i += 256)
    atomicAdd(&lcnt[((unsigned)rows[i]) >> RSHIFT], 1u);
  __syncthreads();
  for (int i = threadIdx.x; i < NBINS; i += 256) {
    unsigned int c = lcnt[i];
    if (c) lbase[i] = atomicAdd(&cursor[i], c);
    lcnt[i] = 0;
  }
  __syncthreads();
  for (int i = start + threadIdx.x; i < end; i += 256) {
    unsigned int r = (unsigned)rows[i];
    int bin = r >> RSHIFT;
    unsigned int p = lbase[bin] + atomicAdd(&lcnt[bin], 1u);
    int s = i / EE;  // support id
    uintx2 rec;
    // bits [16:0]=col, [20:17]=row-in-bin, [22:21]=support
    rec.x = ((unsigned)cols[i]) | ((r & (RR - 1u)) << 17) | (((unsigned)s) << 21);
    rec.y = __float_as_uint(vals[i]);
    __builtin_nontemporal_store(rec, &sorted[p]);
  }
}

// ---- fp16 cast of feat: fb[i] packs elements 2i,2i+1 as half2 (RNE) -------
__global__ __launch_bounds__(256) void cast_kernel(const float* __restrict__ f,
                                                   unsigned int* __restrict__ fb) {
  int i = blockIdx.x * 256 + threadIdx.x;  // over N*F/2 = 6.4M pairs
  float2 a = reinterpret_cast<const float2*>(f)[i];
  __half2 h = __floats2half2_rn(a.x, a.y);
  fb[i] = *reinterpret_cast<unsigned int*>(&h);
}

// ---- fused: branch-free batched accumulate + Wc-fold GEMM + tanh ----------
// Lane l holds feature elements 2l, 2l+1. G slot map: elem 2h+p -> p*64+h.
// MODE: 0 = f32 gathers (float2/lane), 1 = fp16 gathers (half2/lane).
template <int MODE>
__global__ __launch_bounds__(256, 4) void fused_kernel(
    const float* __restrict__ feat, const unsigned int* __restrict__ featb,
    const float* __restrict__ W, const float* __restrict__ Wc,
    const uintx2* __restrict__ sorted, const unsigned int* __restrict__ bin_start,
    float* __restrict__ out) {
  __shared__ float G[SS * RR * FF];  // 4*16*128*4B = 32 KB, G_s contiguous
  const int tid = threadIdx.x;
  const int lane = tid & 63;
  const int wid = tid >> 6;

  float4* gz = (float4*)G;
#pragma unroll
  for (int i = 0; i < (SS * RR * FF / 4) / 256; ++i)  // 8 iters
    gz[tid + i * 256] = make_float4(0.f, 0.f, 0.f, 0.f);
  __syncthreads();

  const int bin = blockIdx.x;
  const unsigned int e0 = bin_start[bin];
  const unsigned int e1 = bin_start[bin + 1];
  const int L = (int)(e1 - e0);
  const unsigned int chunk = (((unsigned)(L + 3) >> 2) + 15u) & ~15u;
  unsigned int e = e0 + (unsigned)wid * chunk;
  unsigned int ew = e + chunk;
  if (ew > e1) ew = e1;

  // Double-buffered 16-record broadcasts; per batch: 16 independent gathers
  // (SGPR-uniform row base + lane voffset), pinned before branch-free consume.
  uintx2 RA;
  if (e + 16 <= ew) RA = __builtin_nontemporal_load(&sorted[e + (lane & 15)]);
  while (e + 16 <= ew) {
    // prefetch next records (clamped address; result used only if valid)
    unsigned int np = e + 16;
    unsigned int pidx = np + (lane & 15);
    if (pidx >= e1) pidx = e1 - 1;  // e1>=1 whenever loop entered
    uintx2 RB = __builtin_nontemporal_load(&sorted[pidx]);

    if constexpr (MODE == 1) {
      unsigned int x[16];
#pragma unroll
      for (int j = 0; j < 16; ++j) {
        unsigned int c =
            ((unsigned)__builtin_amdgcn_readlane((int)RA.x, j)) & 0x1FFFFu;
        x[j] = *(featb + ((size_t)c << 6) + lane);  // 4B = elems 2l,2l+1
      }
      __builtin_amdgcn_sched_barrier(0);
#pragma unroll
      for (int j = 0; j < 16; ++j) {
        unsigned int rx = (unsigned)__builtin_amdgcn_readlane((int)RA.x, j);
        float v = __uint_as_float(
            (unsigned)__builtin_amdgcn_readlane((int)RA.y, j));
        int base = (int)(((rx >> 17) & 63u) << 7);  // (s*16+ro)*128
        float2 xv = __half22float2(*reinterpret_cast<__half2*>(&x[j]));
        atomicAdd(&G[base + lane], v * xv.x);
        atomicAdd(&G[base + 64 + lane], v * xv.y);
      }
    } else {
      float2 x[16];
#pragma unroll
      for (int j = 0; j < 16; ++j) {
        unsigned int c =
            ((unsigned)__builtin_amdgcn_readlane((int)RA.x, j)) & 0x1FFFFu;
        x[j] = *reinterpret_cast<const float2*>(
            &feat[((size_t)c << 7) + (lane << 1)]);
      }
      __builtin_amdgcn_sched_barrier(0);
#pragma unroll
      for (int j = 0; j < 16; ++j) {
        unsigned int rx = (unsigned)__builtin_amdgcn_readlane((int)RA.x, j);
        float v = __uint_as_float(
            (unsigned)__builtin_amdgcn_readlane((int)RA.y, j));
        int base = (int)(((rx >> 17) & 63u) << 7);
        atomicAdd(&G[base + lane], v * x[j].x);
        atomicAdd(&G[base + 64 + lane], v * x[j].y);
      }
    }
    RA = RB;
    e = np;
  }
  // singles tail (<16 edges)
  while (e < ew) {
    uintx2 R1 = sorted[e];
    unsigned int rx = R1.x;
    float v = __uint_as_float(R1.y);
    unsigned int c = rx & 0x1FFFFu;
    int base = (int)(((rx >> 17) & 63u) << 7);
    if constexpr (MODE == 1) {
      unsigned int xx = *(featb + ((size_t)c << 6) + lane);
      float2 xv = __half22float2(*reinterpret_cast<__half2*>(&xx));
      atomicAdd(&G[base + lane], v * xv.x);
      atomicAdd(&G[base + 64 + lane], v * xv.y);
    } else {
      float2 xv = *reinterpret_cast<const float2*>(
          &feat[((size_t)c << 7) + (lane << 1)]);
      atomicAdd(&G[base + lane], v * xv.x);
      atomicAdd(&G[base + 64 + lane], v * xv.y);
    }
    ++e;
  }
  __syncthreads();

  // ---- epilogue: fold supports with Wc, GEMM vs W0,W1, tanh, store ----
  // element k=2h+p lives at slot p*64+h of each G_s row. (validated in R6)
  const float cb0[4] = {Wc[0], Wc[2], Wc[4], Wc[6]};
  const float cb1[4] = {Wc[1], Wc[3], Wc[5], Wc[7]};
  const int tx = tid & 31;  // output cols tx*4 .. tx*4+3
  const int ty = tid >> 5;  // 0..7 -> rows 2ty, 2ty+1
  float acc[2][4];
#pragma unroll
  for (int r = 0; r < 2; ++r)
#pragma unroll
    for (int c = 0; c < 4; ++c) acc[r][c] = 0.f;

  const float* W0 = W;
  const float* W1 = W + FF * OO;
#pragma unroll
  for (int p = 0; p < 2; ++p) {
    for (int h0 = 0; h0 < 64; h0 += 4) {
      float4 as_[2][4];
#pragma unroll
      for (int r = 0; r < 2; ++r)
#pragma unroll
        for (int s = 0; s < 4; ++s)
          as_[r][s] = *reinterpret_cast<const float4*>(
              &G[s * (RR * FF) + ((ty * 2 + r) << 7) + p * 64 + h0]);
#pragma unroll
      for (int i = 0; i < 4; ++i) {
        int k = 2 * (h0 + i) + p;
        float4 b0 = *reinterpret_cast<const float4*>(&W0[k * OO + tx * 4]);
        float4 b1 = *reinterpret_cast<const float4*>(&W1[k * OO + tx * 4]);
#pragma unroll
        for (int r = 0; r < 2; ++r) {
          float g0 = 0.f, g1 = 0.f;
#pragma unroll
          for (int s = 0; s < 4; ++s) {
            float a = reinterpret_cast<const float*>(&as_[r][s])[i];
            g0 += cb0[s] * a;
            g1 += cb1[s] * a;
          }
          acc[r][0] += g0 * b0.x + g1 * b1.x;
          acc[r][1] += g0 * b0.y + g1 * b1.y;
          acc[r][2] += g0 * b0.z + g1 * b1.z;
          acc[r][3] += g0 * b0.w + g1 * b1.w;
        }
      }
    }
  }
#pragma unroll
  for (int r = 0; r < 2; ++r) {
    int row = bin * RR + ty * 2 + r;  // N divisible by 16
    floatx4 o;
    o.x = tanhf(acc[r][0]);
    o.y = tanhf(acc[r][1]);
    o.z = tanhf(acc[r][2]);
    o.w = tanhf(acc[r][3]);
    __builtin_nontemporal_store(o, (floatx4*)&out[(size_t)row * OO + tx * 4]);
  }
}

// ===========================================================================
// FALLBACK PATH (round-1, proven): used only if ws_size is too small
// ===========================================================================
__global__ void compute_V_kernel(const float* __restrict__ W,
                                 const float* __restrict__ Wc,
                                 float* __restrict__ V) {
  int i = blockIdx.x * blockDim.x + threadIdx.x;
  int s = i >> 14;
  int fo = i & 16383;
  V[i] = Wc[s * BBASES + 0] * W[fo] + Wc[s * BBASES + 1] * W[16384 + fo];
}

__global__ __launch_bounds__(256) void scatter_kernel(
    const float* __restrict__ feat, const int* __restrict__ rows,
    const int* __restrict__ cols, const float* __restrict__ vals,
    float* __restrict__ agg) {
  int t = blockIdx.x * blockDim.x + threadIdx.x;
  int e = t >> 5;
  int q = t & 31;
  if (e >= EE) return;
  int r = rows[e];
  int c = cols[e];
  float v = vals[e];
  const float4 x = *reinterpret_cast<const float4*>(&feat[(size_t)c * FF + q * 4]);
  float* dst = &agg[(size_t)r * FF + q * 4];
  unsafeAtomicAdd(dst + 0, v * x.x);
  unsafeAtomicAdd(dst + 1, v * x.y);
  unsafeAtomicAdd(dst + 2, v * x.z);
  unsafeAtomicAdd(dst + 3, v * x.w);
}

__global__ __launch_bounds__(256) void gemm_acc_kernel(
    const float* __restrict__ A, const float* __restrict__ Bv,
    float* __restrict__ C) {
  __shared__ float As[16][64];
  __shared__ float Bs[16][128];
  const int tid = threadIdx.x;
  const int bm0 = blockIdx.x * 64;
  const int tx = tid & 31;
  const int ty = tid >> 5;
  float acc[8][4];
#pragma unroll
  for (int r = 0; r < 8; ++r)
#pragma unroll
    for (int c = 0; c < 4; ++c) acc[r][c] = 0.0f;
  const int ar = tid >> 2;
  const int akq = tid & 3;
  for (int k0 = 0; k0 < FF; k0 += 16) {
    {
      int row = bm0 + ar;
      float4 av = make_float4(0.f, 0.f, 0.f, 0.f);
      if (row < NN)
        av = *reinterpret_cast<const float4*>(&A[(size_t)row * FF + k0 + akq * 4]);
      As[akq * 4 + 0][ar] = av.x;
      As[akq * 4 + 1][ar] = av.y;
      As[akq * 4 + 2][ar] = av.z;
      As[akq * 4 + 3][ar] = av.w;
    }
#pragma unroll
    for (int i = 0; i < 2; ++i) {
      int v = tid + i * 256;
      int kk = v >> 5;
      int cq = v & 31;
      *reinterpret_cast<float4*>(&Bs[kk][cq * 4]) =
          *reinterpret_cast<const float4*>(&Bv[(k0 + kk) * OO + cq * 4]);
    }
    __syncthreads();
#pragma unroll
    for (int kk = 0; kk < 16; ++kk) {
      float4 b = *reinterpret_cast<const float4*>(&Bs[kk][tx * 4]);
#pragma unroll
      for (int r = 0; r < 8; ++r) {
        float a = As[kk][ty * 8 + r];
        acc[r][0] += a * b.x;
        acc[r][1] += a * b.y;
        acc[r][2] += a * b.z;
        acc[r][3] += a * b.w;
      }
    }
    __syncthreads();
  }
#pragma unroll
  for (int r = 0; r < 8; ++r) {
    int row = bm0 + ty * 8 + r;
    if (row < NN) {
      float4* cp = reinterpret_cast<float4*>(&C[(size_t)row * OO + tx * 4]);
      float4 c = *cp;
      c.x += acc[r][0];
      c.y += acc[r][1];
      c.z += acc[r][2];
      c.w += acc[r][3];
      *cp = c;
    }
  }
}

__global__ __launch_bounds__(256) void tanh_kernel(float* __restrict__ out) {
  int i = blockIdx.x * blockDim.x + threadIdx.x;
  float4* p = reinterpret_cast<float4*>(out) + i;
  float4 v = *p;
  v.x = tanhf(v.x);
  v.y = tanhf(v.y);
  v.z = tanhf(v.z);
  v.w = tanhf(v.w);
  *p = v;
}

// ===========================================================================
extern "C" void kernel_launch(void* const* d_in, const int* in_sizes, int n_in,
                              void* d_out, int out_size, void* d_ws,
                              size_t ws_size, hipStream_t stream) {
  const float* feat = (const float*)d_in[0];   // [N, F]
  const float* W = (const float*)d_in[1];      // [B, F, O]
  const float* Wc = (const float*)d_in[2];     // [S, B]
  const int* erows = (const int*)d_in[3];      // [S, E]
  const int* ecols = (const int*)d_in[4];      // [S, E]
  const float* evals = (const float*)d_in[5];  // [S, E]
  float* out = (float*)d_out;                  // [N, O] f32

  unsigned char* ws = (unsigned char*)d_ws;
  unsigned int* hist = (unsigned int*)ws;                 // NBINS
  unsigned int* bin_start = hist + NBINS;                 // NBINS+1
  unsigned int* cursor = bin_start + NBINS + 1;           // NBINS
  size_t sorted_off = (((size_t)(3 * NBINS + 1) * 4) + 255) & ~(size_t)255;
  uintx2* sorted = (uintx2*)(ws + sorted_off);            // TOTE * 8B
  size_t featb_off = sorted_off + (size_t)TOTE * 8;
  unsigned int* featb = (unsigned int*)(ws + featb_off);  // N*F/2 uints (25.6MB)
  size_t needed_f32 = featb_off;
  size_t needed_f16 = featb_off + (size_t)NN * FF * 2;

  if (ws_size >= needed_f32) {
    hipMemsetAsync(hist, 0, (size_t)NBINS * 4, stream);
    hist_kernel<<<RBLOCKS, 256, 0, stream>>>(erows, hist);
    scan_kernel<<<1, 256, 0, stream>>>(hist, bin_start, cursor);
    reorder_kernel<<<RBLOCKS, 256, 0, stream>>>(erows, ecols, evals, cursor, sorted);
    if (ws_size >= needed_f16) {
      cast_kernel<<<(NN * FF / 2) / 256, 256, 0, stream>>>(feat, featb);
      fused_kernel<1><<<NBINS, 256, 0, stream>>>(feat, featb, W, Wc, sorted,
                                                 bin_start, out);
    } else {
      fused_kernel<0><<<NBINS, 256, 0, stream>>>(feat, featb, W, Wc, sorted,
                                                 bin_start, out);
    }
  } else {
    float* V = (float*)d_ws;
    float* agg = V + (size_t)SS * FF * OO;
    compute_V_kernel<<<(SS * FF * OO) / 256, 256, 0, stream>>>(W, Wc, V);
    hipMemsetAsync(out, 0, (size_t)NN * OO * sizeof(float), stream);
    for (int s = 0; s < SS; ++s) {
      hipMemsetAsync(agg, 0, (size_t)NN * FF * sizeof(float), stream);
      scatter_kernel<<<(EE * 32) / 256, 256, 0, stream>>>(
          feat, erows + (size_t)s * EE, ecols + (size_t)s * EE,
          evals + (size_t)s * EE, agg);
      gemm_acc_kernel<<<(NN + 63) / 64, 256, 0, stream>>>(
          agg, V + (size_t)s * FF * OO, out);
    }
    tanh_kernel<<<(NN * OO / 4) / 256, 256, 0, stream>>>(out);
  }
}